// Round 6
// baseline (694.089 us; speedup 1.0000x reference)
//
#include <hip/hip_runtime.h>
#include <hip/hip_bf16.h>
#include <cstdint>
#include <cstddef>

#define NN     8192
#define INF_   256
#define OUTF   128
#define ALPHA  0.2f
#define LOG2E  1.4426950408889634f
#define JSPLIT 2
#define CHUNK  (NN / JSPLIT)   // 4096
#define JT     256             // j-tile per stage/compute iteration
#define NT     (CHUNK / JT)    // 16
#define LROW   66              // LDS mask row stride in dwords (264B: 8B-aligned, bank-spread)

typedef __bf16 bf16;
typedef unsigned int u32;
typedef __attribute__((ext_vector_type(8))) __bf16 bf16x8;
typedef __attribute__((ext_vector_type(4))) float f32x4;
typedef __attribute__((ext_vector_type(4))) unsigned int u32x4;
typedef __attribute__((ext_vector_type(8))) unsigned short u16x8;
typedef __attribute__((ext_vector_type(4))) unsigned short u16x4;

// ---------------------------------------------------------------------------
// Dtype detector: read x's first 2048 uint16s as bf16. fp32 storage -> words
// are fp32 mantissa fragments -> huge exponents; bf16 storage -> N(0,1).
// flag = 1 -> tensors are fp32 (confirmed R2-R5); 0 -> bf16.
// ---------------------------------------------------------------------------
__global__ void gat_detect(const unsigned short* __restrict__ xr, int* __restrict__ flag)
{
    const int lane = threadIdx.x & 63;
    float m = 0.f;
    #pragma unroll
    for (int t = 0; t < 32; ++t) {
        const unsigned short u = xr[lane * 32 + t];
        const float v = fabsf((float)__builtin_bit_cast(bf16, u));
        if (v == v) m = fmaxf(m, v);
    }
    #pragma unroll
    for (int d = 1; d < 64; d <<= 1) m = fmaxf(m, __shfl_xor(m, d));
    if (lane == 0) *flag = (m > 100.f) ? 1 : 0;
}

// dtype-generic helpers ------------------------------------------------------
static __device__ __forceinline__ bf16  loadS(const bf16* p)  { return *p; }
static __device__ __forceinline__ bf16  loadS(const float* p) { return (bf16)*p; }
static __device__ __forceinline__ float loadF(const bf16* p)  { return (float)*p; }
static __device__ __forceinline__ float loadF(const float* p) { return *p; }
static __device__ __forceinline__ void load4(const float* p, bf16* d) {
    const f32x4 v = *(const f32x4*)p;
    #pragma unroll
    for (int t = 0; t < 4; ++t) d[t] = (bf16)v[t];
}
static __device__ __forceinline__ void load4(const bf16* p, bf16* d) {
    *(u16x4*)d = *(const u16x4*)p;
}

// ---------------------------------------------------------------------------
// trans transpose: TT[n][k] = bf16(trans[k][n]).
// ---------------------------------------------------------------------------
template <typename T, int WANT>
__global__ void gat_tt(const T* __restrict__ trans, const int* __restrict__ flag,
                       bf16* __restrict__ TT)
{
    if (*flag != WANT) return;
    const int n = blockIdx.x;      // 0..127
    const int k = threadIdx.x;     // 0..255
    TT[n * INF_ + k] = loadS(trans + k * OUTF + n);
}

// ---------------------------------------------------------------------------
// Projection: h = x @ trans via LDS-staged MFMA. Outputs:
//   HTt tiled: HTt[i>>5][n][i&31]  (attn b-frag loads become contiguous 1KB)
//   e1c/e2c (pre-scaled by log2e)
// ---------------------------------------------------------------------------
template <typename T, int WANT>
__global__ __launch_bounds__(256, 1)
void gat_proj_t(const T* __restrict__ x, const bf16* __restrict__ TT,
                const T* __restrict__ aw, const int* __restrict__ flag,
                bf16* __restrict__ HTt, float* __restrict__ e1c, float* __restrict__ e2c)
{
    if (*flag != WANT) return;

    __shared__ bf16  xs[32][264];
    __shared__ bf16  TTs[128][264];
    __shared__ float hl[32][129];

    const int tid  = threadIdx.x;
    const int wave = tid >> 6;
    const int lane = tid & 63;
    const int m    = lane & 15;
    const int q    = lane >> 4;
    const int i0   = blockIdx.x * 32;

    #pragma unroll
    for (int it = 0; it < 8; ++it) {
        const int e = it * 1024 + tid * 4;
        bf16 tmp[4];
        load4(x + (size_t)i0 * INF_ + e, tmp);
        *(u16x4*)&xs[e >> 8][e & 255] = *(u16x4*)tmp;
    }
    #pragma unroll
    for (int it = 0; it < 16; ++it) {
        const int e = it * 2048 + tid * 8;
        *(u16x8*)&TTs[e >> 8][e & 255] = *(const u16x8*)(TT + e);
    }
    __syncthreads();

    const int rh = wave & 1, fh = wave >> 1;
    f32x4 acc[4] = {};
    #pragma unroll
    for (int ks = 0; ks < INF_; ks += 32) {
        const bf16x8 a = *(const bf16x8*)&xs[rh * 16 + m][ks + q * 8];
        #pragma unroll
        for (int tn = 0; tn < 4; ++tn) {
            const bf16x8 b = *(const bf16x8*)&TTs[fh * 64 + tn * 16 + m][ks + q * 8];
            acc[tn] = __builtin_amdgcn_mfma_f32_16x16x32_bf16(a, b, acc[tn], 0, 0, 0);
        }
    }

    #pragma unroll
    for (int tn = 0; tn < 4; ++tn)
        #pragma unroll
        for (int r = 0; r < 4; ++r)
            hl[rh * 16 + q * 4 + r][fh * 64 + tn * 16 + m] = acc[tn][r];
    __syncthreads();

    {   // e1/e2
        const int r = tid >> 3, seg = tid & 7;
        float s1 = 0.f, s2 = 0.f;
        #pragma unroll
        for (int u = 0; u < 16; ++u) {
            const float hv = hl[r][seg * 16 + u];
            s1 += hv * loadF(aw + seg * 16 + u);
            s2 += hv * loadF(aw + OUTF + seg * 16 + u);
        }
        #pragma unroll
        for (int d = 1; d < 8; d <<= 1) {
            s1 += __shfl_xor(s1, d);
            s2 += __shfl_xor(s2, d);
        }
        if (seg == 0) {
            e1c[i0 + r] = s1 * LOG2E;
            e2c[i0 + r] = s2 * LOG2E;
        }
    }

    {   // HTt tiled write
        const int n = tid >> 1, ih = tid & 1;
        u16x8 p0, p1;
        #pragma unroll
        for (int v = 0; v < 8; ++v) {
            p0[v] = __builtin_bit_cast(unsigned short, (bf16)hl[ih * 16 + v][n]);
            p1[v] = __builtin_bit_cast(unsigned short, (bf16)hl[ih * 16 + 8 + v][n]);
        }
        bf16* base = HTt + (size_t)blockIdx.x * 4096 + n * 32 + ih * 16;
        *(u16x8*)base       = p0;
        *(u16x8*)(base + 8) = p1;
    }
}

// ---------------------------------------------------------------------------
// Fused attention partials with IN-KERNEL adj pack via per-wave LDS transpose.
// Block = 4 waves, 64 rows, one 4096-j chunk, all 128 features. NO barriers:
// each wave stages its OWN 16 rows x 256 j as row-linear dwordx4 streams
// (coalesced 1KB/instr, 16KB in flight), packs !=0 into 0/1 bytes in its own
// LDS region (double-buffered per-wave), then builds P fragments from
// ds_read_b64 mask bytes + e2c and runs 8 MFMAs/step vs L2-hot tiled HTt.
// ---------------------------------------------------------------------------
__global__ __launch_bounds__(256, 2)
void gat_attn(const int* __restrict__ adj, const bf16* __restrict__ HTt,
              const float* __restrict__ e1c, const float* __restrict__ e2c,
              float* __restrict__ numP, float* __restrict__ denP)
{
    __shared__ u32 lm[2][64 * LROW];   // 0/1 byte-mask, per-wave regions

    const int tid  = threadIdx.x;
    const int wave = tid >> 6;
    const int lane = tid & 63;
    const int m    = lane & 15;
    const int q    = lane >> 4;
    const int jc   = blockIdx.x & (JSPLIT - 1);
    const int ig   = blockIdx.x / JSPLIT;
    const int rbase = ig * 64 + wave * 16;
    const int j0    = jc * CHUNK;

    const float e1 = e1c[rbase + m];
    const int* ap = adj + (size_t)rbase * NN + j0 + lane * 4;

    f32x4 acc[8] = {};
    float rs = 0.f;

    // prologue: stage tile 0 (16 coalesced row streams, 16KB/wave in flight)
    u32x4 pre[16];
    #pragma unroll
    for (int r = 0; r < 16; ++r)
        pre[r] = *(const u32x4*)(ap + (size_t)r * NN);

    for (int tl = 0; tl < NT; ++tl) {
        // pack current tile (vmcnt waits land here), row-linear LDS write
        u32* lw = &lm[tl & 1][(wave * 16) * LROW + lane];
        #pragma unroll
        for (int r = 0; r < 16; ++r) {
            const u32x4 v = pre[r];
            lw[r * LROW] = (v[0] ? 0x01u : 0u) | (v[1] ? 0x0100u : 0u) |
                           (v[2] ? 0x010000u : 0u) | (v[3] ? 0x01000000u : 0u);
        }
        // issue next tile's adj loads (in flight across the compute phase)
        if (tl + 1 < NT) {
            const int* apn = ap + (tl + 1) * JT;
            #pragma unroll
            for (int r = 0; r < 16; ++r)
                pre[r] = *(const u32x4*)(apn + (size_t)r * NN);
        }
        // compute: 8 x 32-j MFMA steps from LDS mask (same-wave DS order, no barrier)
        const u32*   lr = &lm[tl & 1][(wave * 16 + m) * LROW + q * 2];
        const float* pe = e2c + j0 + tl * JT + q * 8;
        const bf16*  pb = HTt + ((size_t)(j0 >> 5) + tl * 8) * 4096 + m * 32 + q * 8;
        #pragma unroll
        for (int s = 0; s < 8; ++s) {
            const uint2 w   = *(const uint2*)(lr + s * 8);
            const f32x4 e2a = *(const f32x4*)(pe + s * 32);
            const f32x4 e2b = *(const f32x4*)(pe + s * 32 + 4);
            bf16x8 af;   // A-fragment: A[m][k=q*8+t], leaky-relu in log2 domain
            #pragma unroll
            for (int t = 0; t < 4; ++t) {
                float sv = e1 + e2a[t];
                sv = fmaxf(sv, ALPHA * sv);
                const float p = ((w.x >> (8 * t)) & 0xffu) ? __builtin_amdgcn_exp2f(sv) : 0.f;
                rs += p;
                af[t] = (bf16)p;
            }
            #pragma unroll
            for (int t = 0; t < 4; ++t) {
                float sv = e1 + e2b[t];
                sv = fmaxf(sv, ALPHA * sv);
                const float p = ((w.y >> (8 * t)) & 0xffu) ? __builtin_amdgcn_exp2f(sv) : 0.f;
                rs += p;
                af[4 + t] = (bf16)p;
            }
            const bf16* pbs = pb + (size_t)s * 4096;
            #pragma unroll
            for (int t = 0; t < 8; ++t) {
                const bf16x8 b = __builtin_bit_cast(bf16x8, *(const u32x4*)(pbs + t * 512));
                acc[t] = __builtin_amdgcn_mfma_f32_16x16x32_bf16(af, b, acc[t], 0, 0, 0);
            }
        }
    }

    // row-sum: lanes {m, m+16, m+32, m+48} hold the 4 q-slices of row m
    rs += __shfl_xor(rs, 16);
    rs += __shfl_xor(rs, 32);
    if (lane < 16) denP[(size_t)jc * NN + rbase + m] = rs;

    // C/D layout: col = lane&15, row = q*4 + r -> unique partial slot
    #pragma unroll
    for (int t = 0; t < 8; ++t)
        #pragma unroll
        for (int r = 0; r < 4; ++r)
            numP[((size_t)jc * NN + rbase + q * 4 + r) * OUTF + t * 16 + m] = acc[t][r];
}

// ---------------------------------------------------------------------------
// Finalize: out = elu( (sum_s numP) / (sum_s denP) )
// ---------------------------------------------------------------------------
__global__ __launch_bounds__(256)
void gat_fin(const float* __restrict__ numP, const float* __restrict__ denP,
             const int* __restrict__ flag, void* __restrict__ outv)
{
    const int g  = blockIdx.x * 256 + threadIdx.x;   // one thread per 4 elems
    const int i  = g >> 5;
    const int c4 = g & 31;
    float d = 0.f;
    f32x4 v = {0.f, 0.f, 0.f, 0.f};
    #pragma unroll
    for (int s = 0; s < JSPLIT; ++s) {
        d += denP[(size_t)s * NN + i];
        const f32x4 u = *(const f32x4*)(numP + ((size_t)s * NN + i) * OUTF + c4 * 4);
        #pragma unroll
        for (int t = 0; t < 4; ++t) v[t] += u[t];
    }
    #pragma unroll
    for (int t = 0; t < 4; ++t) {
        const float u = v[t] / d;
        v[t] = (u > 0.f) ? u : __builtin_amdgcn_exp2f(u * LOG2E) - 1.f;  // elu
    }
    const size_t off = (size_t)i * OUTF + c4 * 4;
    if (*flag) {
        *(f32x4*)((float*)outv + off) = v;
    } else {
        u16x4 pk;
        #pragma unroll
        for (int t = 0; t < 4; ++t)
            pk[t] = __builtin_bit_cast(unsigned short, (bf16)v[t]);
        *(u16x4*)((__hip_bfloat16*)outv + off) = pk;
    }
}

// ---------------------------------------------------------------------------
extern "C" void kernel_launch(void* const* d_in, const int* in_sizes, int n_in,
                              void* d_out, int out_size, void* d_ws, size_t ws_size,
                              hipStream_t stream)
{
    const int* adj = (const int*)d_in[1];

    // ws layout (bytes):
    // HTt 2MB | e1c 32KB | e2c 32KB | flag 256B | TT 64KB | numP 8MB | denP 64KB
    char* w = (char*)d_ws;
    bf16*  HTt  = (bf16*)w;   w += (size_t)OUTF * NN * 2;
    float* e1c  = (float*)w;  w += NN * 4;
    float* e2c  = (float*)w;  w += NN * 4;
    int*   flag = (int*)w;    w += 256;
    bf16*  TT   = (bf16*)w;   w += (size_t)OUTF * INF_ * 2;
    float* numP = (float*)w;  w += (size_t)JSPLIT * NN * OUTF * 4;
    float* denP = (float*)w;

    gat_detect<<<1, 64, 0, stream>>>((const unsigned short*)d_in[0], flag);

    gat_tt<float, 1><<<OUTF, INF_, 0, stream>>>((const float*)d_in[2], flag, TT);
    gat_tt<bf16, 0><<<OUTF, INF_, 0, stream>>>((const bf16*)d_in[2], flag, TT);

    gat_proj_t<float, 1><<<NN / 32, 256, 0, stream>>>(
        (const float*)d_in[0], TT, (const float*)d_in[3], flag, HTt, e1c, e2c);
    gat_proj_t<bf16, 0><<<NN / 32, 256, 0, stream>>>(
        (const bf16*)d_in[0], TT, (const bf16*)d_in[3], flag, HTt, e1c, e2c);

    gat_attn<<<(NN / 64) * JSPLIT, 256, 0, stream>>>(adj, HTt, e1c, e2c, numP, denP);

    gat_fin<<<NN * OUTF / 4 / 256, 256, 0, stream>>>(numP, denP, flag, d_out);
}

// Round 7
// 462.989 us; speedup vs baseline: 1.4991x; 1.4991x over previous
//
#include <hip/hip_runtime.h>
#include <hip/hip_bf16.h>
#include <cstdint>
#include <cstddef>

#define NN     8192
#define INF_   256
#define OUTF   128
#define ALPHA  0.2f
#define LOG2E  1.4426950408889634f
#define JSPLIT 8
#define CHUNK  (NN / JSPLIT)   // 1024 j per block

typedef __bf16 bf16;
typedef unsigned int u32;
typedef unsigned long long u64;
typedef __attribute__((ext_vector_type(8))) __bf16 bf16x8;
typedef __attribute__((ext_vector_type(4))) float f32x4;
typedef __attribute__((ext_vector_type(4))) unsigned int u32x4;
typedef __attribute__((ext_vector_type(8))) unsigned short u16x8;
typedef __attribute__((ext_vector_type(4))) unsigned short u16x4;

// ---------------------------------------------------------------------------
// Dtype detector: read x's first 2048 uint16s as bf16. fp32 storage -> words
// are fp32 mantissa fragments -> huge exponents; bf16 storage -> N(0,1).
// flag = 1 -> tensors are fp32 (confirmed R2-R6); 0 -> bf16.
// ---------------------------------------------------------------------------
__global__ void gat_detect(const unsigned short* __restrict__ xr, int* __restrict__ flag)
{
    const int lane = threadIdx.x & 63;
    float m = 0.f;
    #pragma unroll
    for (int t = 0; t < 32; ++t) {
        const unsigned short u = xr[lane * 32 + t];
        const float v = fabsf((float)__builtin_bit_cast(bf16, u));
        if (v == v) m = fmaxf(m, v);
    }
    #pragma unroll
    for (int d = 1; d < 64; d <<= 1) m = fmaxf(m, __shfl_xor(m, d));
    if (lane == 0) *flag = (m > 100.f) ? 1 : 0;
}

// dtype-generic helpers ------------------------------------------------------
static __device__ __forceinline__ bf16  loadS(const bf16* p)  { return *p; }
static __device__ __forceinline__ bf16  loadS(const float* p) { return (bf16)*p; }
static __device__ __forceinline__ float loadF(const bf16* p)  { return (float)*p; }
static __device__ __forceinline__ float loadF(const float* p) { return *p; }
static __device__ __forceinline__ void load4(const float* p, bf16* d) {
    const f32x4 v = *(const f32x4*)p;
    #pragma unroll
    for (int t = 0; t < 4; ++t) d[t] = (bf16)v[t];
}
static __device__ __forceinline__ void load4(const bf16* p, bf16* d) {
    *(u16x4*)d = *(const u16x4*)p;
}

// ---------------------------------------------------------------------------
// trans transpose: TT[n][k] = bf16(trans[k][n]).
// ---------------------------------------------------------------------------
template <typename T, int WANT>
__global__ void gat_tt(const T* __restrict__ trans, const int* __restrict__ flag,
                       bf16* __restrict__ TT)
{
    if (*flag != WANT) return;
    const int n = blockIdx.x;      // 0..127
    const int k = threadIdx.x;     // 0..255
    TT[n * INF_ + k] = loadS(trans + k * OUTF + n);
}

// ---------------------------------------------------------------------------
// adj bitpack, TRANSPOSED output: maskT[j>>6][row] = 64-bit mask, bit b
// <-> adj[row][ (j>>6)*64 + b ].  Loads are row-linear coalesced dword
// streams (this kernel carries the structural 256 MB adj read at HBM rate);
// stores are 8B/window scattered but tiny (8 MB total, write-combined).
// ---------------------------------------------------------------------------
__global__ __launch_bounds__(256)
void gat_pack(const int* __restrict__ adj, u64* __restrict__ maskT)
{
    const int wave = threadIdx.x >> 6;
    const int lane = threadIdx.x & 63;
    const int row  = blockIdx.x;
    const int* ap = adj + (size_t)row * NN + wave * 2048;
    u64*       mp = maskT + (size_t)(wave * 32) * NN + row;

    int v[32];
    #pragma unroll
    for (int u = 0; u < 32; ++u) v[u] = ap[u * 64 + lane];   // j = (wave*32+u)*64 + lane
    #pragma unroll
    for (int u = 0; u < 32; ++u) {
        const u64 b = __ballot(v[u] != 0);
        if (lane == 0) mp[(size_t)u * NN] = b;
    }
}

// ---------------------------------------------------------------------------
// Projection: h = x @ trans via LDS-staged MFMA. Outputs:
//   HTt tiled: HTt[i>>5][n][i&31]  (attn b-frag loads become contiguous 1KB)
//   e1c/e2c (pre-scaled by log2e)
// ---------------------------------------------------------------------------
template <typename T, int WANT>
__global__ __launch_bounds__(256, 1)
void gat_proj_t(const T* __restrict__ x, const bf16* __restrict__ TT,
                const T* __restrict__ aw, const int* __restrict__ flag,
                bf16* __restrict__ HTt, float* __restrict__ e1c, float* __restrict__ e2c)
{
    if (*flag != WANT) return;

    __shared__ bf16  xs[32][264];
    __shared__ bf16  TTs[128][264];
    __shared__ float hl[32][129];

    const int tid  = threadIdx.x;
    const int wave = tid >> 6;
    const int lane = tid & 63;
    const int m    = lane & 15;
    const int q    = lane >> 4;
    const int i0   = blockIdx.x * 32;

    #pragma unroll
    for (int it = 0; it < 8; ++it) {
        const int e = it * 1024 + tid * 4;
        bf16 tmp[4];
        load4(x + (size_t)i0 * INF_ + e, tmp);
        *(u16x4*)&xs[e >> 8][e & 255] = *(u16x4*)tmp;
    }
    #pragma unroll
    for (int it = 0; it < 16; ++it) {
        const int e = it * 2048 + tid * 8;
        *(u16x8*)&TTs[e >> 8][e & 255] = *(const u16x8*)(TT + e);
    }
    __syncthreads();

    const int rh = wave & 1, fh = wave >> 1;
    f32x4 acc[4] = {};
    #pragma unroll
    for (int ks = 0; ks < INF_; ks += 32) {
        const bf16x8 a = *(const bf16x8*)&xs[rh * 16 + m][ks + q * 8];
        #pragma unroll
        for (int tn = 0; tn < 4; ++tn) {
            const bf16x8 b = *(const bf16x8*)&TTs[fh * 64 + tn * 16 + m][ks + q * 8];
            acc[tn] = __builtin_amdgcn_mfma_f32_16x16x32_bf16(a, b, acc[tn], 0, 0, 0);
        }
    }

    #pragma unroll
    for (int tn = 0; tn < 4; ++tn)
        #pragma unroll
        for (int r = 0; r < 4; ++r)
            hl[rh * 16 + q * 4 + r][fh * 64 + tn * 16 + m] = acc[tn][r];
    __syncthreads();

    {   // e1/e2
        const int r = tid >> 3, seg = tid & 7;
        float s1 = 0.f, s2 = 0.f;
        #pragma unroll
        for (int u = 0; u < 16; ++u) {
            const float hv = hl[r][seg * 16 + u];
            s1 += hv * loadF(aw + seg * 16 + u);
            s2 += hv * loadF(aw + OUTF + seg * 16 + u);
        }
        #pragma unroll
        for (int d = 1; d < 8; d <<= 1) {
            s1 += __shfl_xor(s1, d);
            s2 += __shfl_xor(s2, d);
        }
        if (seg == 0) {
            e1c[i0 + r] = s1 * LOG2E;
            e2c[i0 + r] = s2 * LOG2E;
        }
    }

    {   // HTt tiled write
        const int n = tid >> 1, ih = tid & 1;
        u16x8 p0, p1;
        #pragma unroll
        for (int v = 0; v < 8; ++v) {
            p0[v] = __builtin_bit_cast(unsigned short, (bf16)hl[ih * 16 + v][n]);
            p1[v] = __builtin_bit_cast(unsigned short, (bf16)hl[ih * 16 + 8 + v][n]);
        }
        bf16* base = HTt + (size_t)blockIdx.x * 4096 + n * 32 + ih * 16;
        *(u16x8*)base       = p0;
        *(u16x8*)(base + 8) = p1;
    }
}

// ---------------------------------------------------------------------------
// Masked-softmax-attention partials from transposed bitmask. High occupancy:
// grid 1024 (4 blocks/CU, 16 waves/CU), no LDS, no barriers, no manual
// prefetch -- cross-wave overlap hides latency. Block = 4 waves x 16 rows
// (64 rows) x one 1024-j chunk x all 128 features. Mask: 16 consecutive u64
// per wave per 64-j window (broadcast over q). HTt b-frags contiguous 1KB.
// jc = bid & 7 pins each XCD to one HTt/mask j-slice (L2-resident).
// ---------------------------------------------------------------------------
__global__ __launch_bounds__(256, 4)
void gat_attn(const u64* __restrict__ maskT, const bf16* __restrict__ HTt,
              const float* __restrict__ e1c, const float* __restrict__ e2c,
              float* __restrict__ numP, float* __restrict__ denP)
{
    const int tid  = threadIdx.x;
    const int wave = tid >> 6;
    const int lane = tid & 63;
    const int m    = lane & 15;
    const int q    = lane >> 4;
    const int jc   = blockIdx.x & (JSPLIT - 1);
    const int ig   = blockIdx.x / JSPLIT;
    const int rbase = ig * 64 + wave * 16;
    const int row   = rbase + m;
    const int j0    = jc * CHUNK;

    const float e1 = e1c[row];
    const u64*   pm = maskT + (size_t)(j0 >> 6) * NN + row;
    const float* pe = e2c + j0 + q * 8;
    const bf16*  pb = HTt + (size_t)(j0 >> 5) * 4096 + m * 32 + q * 8;

    f32x4 acc[8] = {};
    float rs = 0.f;

    for (int w = 0; w < CHUNK / 64; ++w) {          // 16 windows of 64 j
        const u64 mw = pm[(size_t)w * NN];
        #pragma unroll
        for (int h = 0; h < 2; ++h) {               // two 32-j MFMA steps
            const u32 wb = h ? (u32)(mw >> 32) : (u32)mw;
            const int j  = w * 64 + h * 32;
            const f32x4 e2a = *(const f32x4*)(pe + j);
            const f32x4 e2b = *(const f32x4*)(pe + j + 4);

            bf16x8 af;   // A-fragment: A[m][k=q*8+t], leaky-relu in log2 domain
            #pragma unroll
            for (int t = 0; t < 4; ++t) {
                float sv = e1 + e2a[t];
                sv = fmaxf(sv, ALPHA * sv);
                const float p = ((wb >> (q * 8 + t)) & 1u) ? __builtin_amdgcn_exp2f(sv) : 0.f;
                rs += p;
                af[t] = (bf16)p;
            }
            #pragma unroll
            for (int t = 0; t < 4; ++t) {
                float sv = e1 + e2b[t];
                sv = fmaxf(sv, ALPHA * sv);
                const float p = ((wb >> (q * 8 + 4 + t)) & 1u) ? __builtin_amdgcn_exp2f(sv) : 0.f;
                rs += p;
                af[4 + t] = (bf16)p;
            }

            const bf16* pbs = pb + (size_t)(j >> 5) * 4096;
            #pragma unroll
            for (int t = 0; t < 8; ++t) {
                const bf16x8 b = __builtin_bit_cast(bf16x8, *(const u32x4*)(pbs + t * 512));
                acc[t] = __builtin_amdgcn_mfma_f32_16x16x32_bf16(af, b, acc[t], 0, 0, 0);
            }
        }
    }

    // row-sum: lanes {m, m+16, m+32, m+48} hold the 4 q-slices of row m
    rs += __shfl_xor(rs, 16);
    rs += __shfl_xor(rs, 32);
    if (lane < 16) denP[(size_t)jc * NN + rbase + m] = rs;

    // C/D layout: col = lane&15, row = q*4 + r -> unique partial slot
    #pragma unroll
    for (int t = 0; t < 8; ++t)
        #pragma unroll
        for (int r = 0; r < 4; ++r)
            numP[((size_t)jc * NN + rbase + q * 4 + r) * OUTF + t * 16 + m] = acc[t][r];
}

// ---------------------------------------------------------------------------
// Finalize: out = elu( (sum_s numP) / (sum_s denP) )
// ---------------------------------------------------------------------------
__global__ __launch_bounds__(256)
void gat_fin(const float* __restrict__ numP, const float* __restrict__ denP,
             const int* __restrict__ flag, void* __restrict__ outv)
{
    const int g  = blockIdx.x * 256 + threadIdx.x;   // one thread per 4 elems
    const int i  = g >> 5;
    const int c4 = g & 31;
    float d = 0.f;
    f32x4 v = {0.f, 0.f, 0.f, 0.f};
    #pragma unroll
    for (int s = 0; s < JSPLIT; ++s) {
        d += denP[(size_t)s * NN + i];
        const f32x4 u = *(const f32x4*)(numP + ((size_t)s * NN + i) * OUTF + c4 * 4);
        #pragma unroll
        for (int t = 0; t < 4; ++t) v[t] += u[t];
    }
    #pragma unroll
    for (int t = 0; t < 4; ++t) {
        const float u = v[t] / d;
        v[t] = (u > 0.f) ? u : __builtin_amdgcn_exp2f(u * LOG2E) - 1.f;  // elu
    }
    const size_t off = (size_t)i * OUTF + c4 * 4;
    if (*flag) {
        *(f32x4*)((float*)outv + off) = v;
    } else {
        u16x4 pk;
        #pragma unroll
        for (int t = 0; t < 4; ++t)
            pk[t] = __builtin_bit_cast(unsigned short, (bf16)v[t]);
        *(u16x4*)((__hip_bfloat16*)outv + off) = pk;
    }
}

// ---------------------------------------------------------------------------
extern "C" void kernel_launch(void* const* d_in, const int* in_sizes, int n_in,
                              void* d_out, int out_size, void* d_ws, size_t ws_size,
                              hipStream_t stream)
{
    const int* adj = (const int*)d_in[1];

    // ws layout (bytes):
    // HTt 2MB | e1c 32KB | e2c 32KB | flag 256B | TT 64KB | maskT 8MB
    // | numP 32MB | denP 256KB   (~42 MB total)
    char* w = (char*)d_ws;
    bf16*  HTt   = (bf16*)w;   w += (size_t)OUTF * NN * 2;
    float* e1c   = (float*)w;  w += NN * 4;
    float* e2c   = (float*)w;  w += NN * 4;
    int*   flag  = (int*)w;    w += 256;
    bf16*  TT    = (bf16*)w;   w += (size_t)OUTF * INF_ * 2;
    u64*   maskT = (u64*)w;    w += (size_t)(NN / 64) * NN * 8;
    float* numP  = (float*)w;  w += (size_t)JSPLIT * NN * OUTF * 4;
    float* denP  = (float*)w;

    gat_detect<<<1, 64, 0, stream>>>((const unsigned short*)d_in[0], flag);

    gat_tt<float, 1><<<OUTF, INF_, 0, stream>>>((const float*)d_in[2], flag, TT);
    gat_tt<bf16, 0><<<OUTF, INF_, 0, stream>>>((const bf16*)d_in[2], flag, TT);

    gat_pack<<<NN, 256, 0, stream>>>(adj, maskT);

    gat_proj_t<float, 1><<<NN / 32, 256, 0, stream>>>(
        (const float*)d_in[0], TT, (const float*)d_in[3], flag, HTt, e1c, e2c);
    gat_proj_t<bf16, 0><<<NN / 32, 256, 0, stream>>>(
        (const bf16*)d_in[0], TT, (const bf16*)d_in[3], flag, HTt, e1c, e2c);

    gat_attn<<<(NN / 64) * JSPLIT, 256, 0, stream>>>(maskT, HTt, e1c, e2c, numP, denP);

    gat_fin<<<NN * OUTF / 4 / 256, 256, 0, stream>>>(numP, denP, flag, d_out);
}

// Round 8
// 434.114 us; speedup vs baseline: 1.5989x; 1.0665x over previous
//
#include <hip/hip_runtime.h>
#include <hip/hip_bf16.h>
#include <cstdint>
#include <cstddef>

#define NN     8192
#define INF_   256
#define OUTF   128
#define ALPHA  0.2f
#define LOG2E  1.4426950408889634f
#define JSPLIT 8
#define CHUNK  (NN / JSPLIT)   // 1024 j per block

typedef __bf16 bf16;
typedef unsigned int u32;
typedef unsigned long long u64;
typedef __attribute__((ext_vector_type(8))) __bf16 bf16x8;
typedef __attribute__((ext_vector_type(4))) float f32x4;
typedef __attribute__((ext_vector_type(4))) unsigned int u32x4;
typedef __attribute__((ext_vector_type(8))) unsigned short u16x8;
typedef __attribute__((ext_vector_type(4))) unsigned short u16x4;

// ---------------------------------------------------------------------------
// Dtype detector: read x's first 2048 uint16s as bf16. fp32 storage -> words
// are fp32 mantissa fragments -> huge exponents; bf16 storage -> N(0,1).
// flag = 1 -> tensors are fp32 (confirmed R2-R7); 0 -> bf16.
// ---------------------------------------------------------------------------
__global__ void gat_detect(const unsigned short* __restrict__ xr, int* __restrict__ flag)
{
    const int lane = threadIdx.x & 63;
    float m = 0.f;
    #pragma unroll
    for (int t = 0; t < 32; ++t) {
        const unsigned short u = xr[lane * 32 + t];
        const float v = fabsf((float)__builtin_bit_cast(bf16, u));
        if (v == v) m = fmaxf(m, v);
    }
    #pragma unroll
    for (int d = 1; d < 64; d <<= 1) m = fmaxf(m, __shfl_xor(m, d));
    if (lane == 0) *flag = (m > 100.f) ? 1 : 0;
}

// dtype-generic helpers ------------------------------------------------------
static __device__ __forceinline__ bf16  loadS(const bf16* p)  { return *p; }
static __device__ __forceinline__ bf16  loadS(const float* p) { return (bf16)*p; }
static __device__ __forceinline__ float loadF(const bf16* p)  { return (float)*p; }
static __device__ __forceinline__ float loadF(const float* p) { return *p; }
static __device__ __forceinline__ void load4(const float* p, bf16* d) {
    const f32x4 v = *(const f32x4*)p;
    #pragma unroll
    for (int t = 0; t < 4; ++t) d[t] = (bf16)v[t];
}
static __device__ __forceinline__ void load4(const bf16* p, bf16* d) {
    *(u16x4*)d = *(const u16x4*)p;
}

// ---------------------------------------------------------------------------
// trans transpose: TT[n][k] = bf16(trans[k][n]).
// ---------------------------------------------------------------------------
template <typename T, int WANT>
__global__ void gat_tt(const T* __restrict__ trans, const int* __restrict__ flag,
                       bf16* __restrict__ TT)
{
    if (*flag != WANT) return;
    const int n = blockIdx.x;      // 0..127
    const int k = threadIdx.x;     // 0..255
    TT[n * INF_ + k] = loadS(trans + k * OUTF + n);
}

// ---------------------------------------------------------------------------
// Projection: h = x @ trans via LDS-staged MFMA. Outputs:
//   HTt tiled: HTt[i>>5][n][i&31]  (attn b-frag loads become contiguous 1KB)
//   e1c/e2c (pre-scaled by log2e)
// ---------------------------------------------------------------------------
template <typename T, int WANT>
__global__ __launch_bounds__(256, 1)
void gat_proj_t(const T* __restrict__ x, const bf16* __restrict__ TT,
                const T* __restrict__ aw, const int* __restrict__ flag,
                bf16* __restrict__ HTt, float* __restrict__ e1c, float* __restrict__ e2c)
{
    if (*flag != WANT) return;

    __shared__ bf16  xs[32][264];
    __shared__ bf16  TTs[128][264];
    __shared__ float hl[32][129];

    const int tid  = threadIdx.x;
    const int wave = tid >> 6;
    const int lane = tid & 63;
    const int m    = lane & 15;
    const int q    = lane >> 4;
    const int i0   = blockIdx.x * 32;

    #pragma unroll
    for (int it = 0; it < 8; ++it) {
        const int e = it * 1024 + tid * 4;
        bf16 tmp[4];
        load4(x + (size_t)i0 * INF_ + e, tmp);
        *(u16x4*)&xs[e >> 8][e & 255] = *(u16x4*)tmp;
    }
    #pragma unroll
    for (int it = 0; it < 16; ++it) {
        const int e = it * 2048 + tid * 8;
        *(u16x8*)&TTs[e >> 8][e & 255] = *(const u16x8*)(TT + e);
    }
    __syncthreads();

    const int rh = wave & 1, fh = wave >> 1;
    f32x4 acc[4] = {};
    #pragma unroll
    for (int ks = 0; ks < INF_; ks += 32) {
        const bf16x8 a = *(const bf16x8*)&xs[rh * 16 + m][ks + q * 8];
        #pragma unroll
        for (int tn = 0; tn < 4; ++tn) {
            const bf16x8 b = *(const bf16x8*)&TTs[fh * 64 + tn * 16 + m][ks + q * 8];
            acc[tn] = __builtin_amdgcn_mfma_f32_16x16x32_bf16(a, b, acc[tn], 0, 0, 0);
        }
    }

    #pragma unroll
    for (int tn = 0; tn < 4; ++tn)
        #pragma unroll
        for (int r = 0; r < 4; ++r)
            hl[rh * 16 + q * 4 + r][fh * 64 + tn * 16 + m] = acc[tn][r];
    __syncthreads();

    {   // e1/e2
        const int r = tid >> 3, seg = tid & 7;
        float s1 = 0.f, s2 = 0.f;
        #pragma unroll
        for (int u = 0; u < 16; ++u) {
            const float hv = hl[r][seg * 16 + u];
            s1 += hv * loadF(aw + seg * 16 + u);
            s2 += hv * loadF(aw + OUTF + seg * 16 + u);
        }
        #pragma unroll
        for (int d = 1; d < 8; d <<= 1) {
            s1 += __shfl_xor(s1, d);
            s2 += __shfl_xor(s2, d);
        }
        if (seg == 0) {
            e1c[i0 + r] = s1 * LOG2E;
            e2c[i0 + r] = s2 * LOG2E;
        }
    }

    {   // HTt tiled write
        const int n = tid >> 1, ih = tid & 1;
        u16x8 p0, p1;
        #pragma unroll
        for (int v = 0; v < 8; ++v) {
            p0[v] = __builtin_bit_cast(unsigned short, (bf16)hl[ih * 16 + v][n]);
            p1[v] = __builtin_bit_cast(unsigned short, (bf16)hl[ih * 16 + 8 + v][n]);
        }
        bf16* base = HTt + (size_t)blockIdx.x * 4096 + n * 32 + ih * 16;
        *(u16x8*)base       = p0;
        *(u16x8*)(base + 8) = p1;
    }
}

// ---------------------------------------------------------------------------
// FUSED adj-stream + masked-softmax-attention partials. The 256 MB adj read
// happens HERE, row-linear coalesced, overlapped with P-build and MFMA.
// Grid 1024 = 4 blocks/CU (proven R7 occupancy recipe), no LDS, no barriers,
// no manual prefetch. Per wave, per 64-j window:
//   16 coalesced dword loads (row r, j = w*64 + lane)  -> 4 KB HBM stream
//   16 __ballot -> u64 row-masks; lane r keeps row r's mask (cndmask)
//   __shfl(mask, m) -> lane (m,q) gets row m's bits for its A-fragment
//   2 x 32-j MFMA steps vs L2-hot tiled HTt (8 MFMAs each, all 128 features)
// jc = bid & 7 pins each XCD to one HTt/e2c j-slice (L2-resident).
// ---------------------------------------------------------------------------
__global__ __launch_bounds__(256, 4)
void gat_attn(const int* __restrict__ adj, const bf16* __restrict__ HTt,
              const float* __restrict__ e1c, const float* __restrict__ e2c,
              float* __restrict__ numP, float* __restrict__ denP)
{
    const int tid  = threadIdx.x;
    const int wave = tid >> 6;
    const int lane = tid & 63;
    const int m    = lane & 15;
    const int q    = lane >> 4;
    const int jc   = blockIdx.x & (JSPLIT - 1);
    const int ig   = blockIdx.x / JSPLIT;
    const int rbase = ig * 64 + wave * 16;
    const int j0    = jc * CHUNK;

    const float e1 = e1c[rbase + m];
    const int*   ap = adj + (size_t)rbase * NN + j0 + lane;
    const float* pe = e2c + j0 + q * 8;
    const bf16*  pb = HTt + (size_t)(j0 >> 5) * 4096 + m * 32 + q * 8;

    f32x4 acc[8] = {};
    float rs = 0.f;

    for (int w = 0; w < CHUNK / 64; ++w) {          // 16 windows of 64 j
        // stream this wave's 16 rows x 64 j of adj (bit j = lane for ballot)
        int v[16];
        #pragma unroll
        for (int r = 0; r < 16; ++r)
            v[r] = ap[(size_t)r * NN + w * 64];

        // pack: row r -> 64-bit mask; park row r's mask in lane r
        u32 mlo = 0, mhi = 0;
        #pragma unroll
        for (int r = 0; r < 16; ++r) {
            const u64 b = __ballot(v[r] != 0);
            if (lane == r) { mlo = (u32)b; mhi = (u32)(b >> 32); }
        }
        // lane (m,q) pulls row m's mask halves
        const u32 wlo = __shfl(mlo, m);
        const u32 whi = __shfl(mhi, m);

        #pragma unroll
        for (int h = 0; h < 2; ++h) {               // two 32-j MFMA steps
            const u32 wb = h ? whi : wlo;
            const int j  = w * 64 + h * 32;
            const f32x4 e2a = *(const f32x4*)(pe + j);
            const f32x4 e2b = *(const f32x4*)(pe + j + 4);

            bf16x8 af;   // A-fragment: A[m][k=q*8+t], leaky-relu in log2 domain
            #pragma unroll
            for (int t = 0; t < 4; ++t) {
                float sv = e1 + e2a[t];
                sv = fmaxf(sv, ALPHA * sv);
                const float p = ((wb >> (q * 8 + t)) & 1u) ? __builtin_amdgcn_exp2f(sv) : 0.f;
                rs += p;
                af[t] = (bf16)p;
            }
            #pragma unroll
            for (int t = 0; t < 4; ++t) {
                float sv = e1 + e2b[t];
                sv = fmaxf(sv, ALPHA * sv);
                const float p = ((wb >> (q * 8 + 4 + t)) & 1u) ? __builtin_amdgcn_exp2f(sv) : 0.f;
                rs += p;
                af[4 + t] = (bf16)p;
            }

            const bf16* pbs = pb + (size_t)(j >> 5) * 4096;
            #pragma unroll
            for (int t = 0; t < 8; ++t) {
                const bf16x8 b = __builtin_bit_cast(bf16x8, *(const u32x4*)(pbs + t * 512));
                acc[t] = __builtin_amdgcn_mfma_f32_16x16x32_bf16(af, b, acc[t], 0, 0, 0);
            }
        }
    }

    // row-sum: lanes {m, m+16, m+32, m+48} hold the 4 q-slices of row m
    rs += __shfl_xor(rs, 16);
    rs += __shfl_xor(rs, 32);
    if (lane < 16) denP[(size_t)jc * NN + rbase + m] = rs;

    // C/D layout: col = lane&15, row = q*4 + r -> unique partial slot
    #pragma unroll
    for (int t = 0; t < 8; ++t)
        #pragma unroll
        for (int r = 0; r < 4; ++r)
            numP[((size_t)jc * NN + rbase + q * 4 + r) * OUTF + t * 16 + m] = acc[t][r];
}

// ---------------------------------------------------------------------------
// Finalize: out = elu( (sum_s numP) / (sum_s denP) )
// ---------------------------------------------------------------------------
__global__ __launch_bounds__(256)
void gat_fin(const float* __restrict__ numP, const float* __restrict__ denP,
             const int* __restrict__ flag, void* __restrict__ outv)
{
    const int g  = blockIdx.x * 256 + threadIdx.x;   // one thread per 4 elems
    const int i  = g >> 5;
    const int c4 = g & 31;
    float d = 0.f;
    f32x4 v = {0.f, 0.f, 0.f, 0.f};
    #pragma unroll
    for (int s = 0; s < JSPLIT; ++s) {
        d += denP[(size_t)s * NN + i];
        const f32x4 u = *(const f32x4*)(numP + ((size_t)s * NN + i) * OUTF + c4 * 4);
        #pragma unroll
        for (int t = 0; t < 4; ++t) v[t] += u[t];
    }
    #pragma unroll
    for (int t = 0; t < 4; ++t) {
        const float u = v[t] / d;
        v[t] = (u > 0.f) ? u : __builtin_amdgcn_exp2f(u * LOG2E) - 1.f;  // elu
    }
    const size_t off = (size_t)i * OUTF + c4 * 4;
    if (*flag) {
        *(f32x4*)((float*)outv + off) = v;
    } else {
        u16x4 pk;
        #pragma unroll
        for (int t = 0; t < 4; ++t)
            pk[t] = __builtin_bit_cast(unsigned short, (bf16)v[t]);
        *(u16x4*)((__hip_bfloat16*)outv + off) = pk;
    }
}

// ---------------------------------------------------------------------------
extern "C" void kernel_launch(void* const* d_in, const int* in_sizes, int n_in,
                              void* d_out, int out_size, void* d_ws, size_t ws_size,
                              hipStream_t stream)
{
    const int* adj = (const int*)d_in[1];

    // ws layout (bytes):
    // HTt 2MB | e1c 32KB | e2c 32KB | flag 256B | TT 64KB | numP 32MB | denP 256KB
    char* w = (char*)d_ws;
    bf16*  HTt   = (bf16*)w;   w += (size_t)OUTF * NN * 2;
    float* e1c   = (float*)w;  w += NN * 4;
    float* e2c   = (float*)w;  w += NN * 4;
    int*   flag  = (int*)w;    w += 256;
    bf16*  TT    = (bf16*)w;   w += (size_t)OUTF * INF_ * 2;
    float* numP  = (float*)w;  w += (size_t)JSPLIT * NN * OUTF * 4;
    float* denP  = (float*)w;

    gat_detect<<<1, 64, 0, stream>>>((const unsigned short*)d_in[0], flag);

    gat_tt<float, 1><<<OUTF, INF_, 0, stream>>>((const float*)d_in[2], flag, TT);
    gat_tt<bf16, 0><<<OUTF, INF_, 0, stream>>>((const bf16*)d_in[2], flag, TT);

    gat_proj_t<float, 1><<<NN / 32, 256, 0, stream>>>(
        (const float*)d_in[0], TT, (const float*)d_in[3], flag, HTt, e1c, e2c);
    gat_proj_t<bf16, 0><<<NN / 32, 256, 0, stream>>>(
        (const bf16*)d_in[0], TT, (const bf16*)d_in[3], flag, HTt, e1c, e2c);

    gat_attn<<<(NN / 64) * JSPLIT, 256, 0, stream>>>(adj, HTt, e1c, e2c, numP, denP);

    gat_fin<<<NN * OUTF / 4 / 256, 256, 0, stream>>>(numP, denP, flag, d_out);
}